// Round 5
// baseline (223.016 us; speedup 1.0000x reference)
//
#include <hip/hip_runtime.h>
#include <hip/hip_bf16.h>
#include <stdint.h>

typedef __bf16 bf16_t;
typedef bf16_t bf16x8 __attribute__((ext_vector_type(8)));
typedef bf16_t bf16x4 __attribute__((ext_vector_type(4)));
typedef float  f32x4  __attribute__((ext_vector_type(4)));
typedef float  f32x16 __attribute__((ext_vector_type(16)));

#define MFMA_BF16 __builtin_amdgcn_mfma_f32_16x16x32_bf16
#define MFMA32    __builtin_amdgcn_mfma_f32_32x32x16_bf16

constexpr int BB = 4, SS = 2048, HH = 8;
constexpr float QK_SCALE = 0.08838834764831845f;          // 1/sqrt(128)
constexpr float LOG2E    = 1.4426950408889634f;
constexpr float QSCL     = QK_SCALE * LOG2E;              // scores in log2 domain

__device__ __forceinline__ float exp2_fast(float x) {
#if __has_builtin(__builtin_amdgcn_exp2f)
    return __builtin_amdgcn_exp2f(x);
#else
    return __expf(x * 0.6931471805599453f);
#endif
}

// async global->LDS DMA, 16B per lane; lds ptr must be wave-uniform base
__device__ __forceinline__ void dma16(const bf16_t* g, bf16_t* l) {
    __builtin_amdgcn_global_load_lds(
        (const __attribute__((address_space(1))) void*)g,
        (__attribute__((address_space(3))) void*)l, 16, 0, 0);
}

// ---------------------------------------------------------------------------
// Prep: blocks 0..127 transpose weights (QSCL folded into WqT); blocks
// 128..895 convert q/k/v fp32 -> bf16 into Abf[3][8192][128].
// ---------------------------------------------------------------------------
__global__ void prep_kernel(const float* __restrict__ q, const float* __restrict__ k,
                            const float* __restrict__ v,
                            const float* __restrict__ Wq, const float* __restrict__ Wk,
                            const float* __restrict__ Wv, const float* __restrict__ Wo,
                            bf16_t* __restrict__ WqT, bf16_t* __restrict__ WkT,
                            bf16_t* __restrict__ WvT, bf16_t* __restrict__ WoT,
                            bf16_t* __restrict__ Abf)
{
    int bid = blockIdx.x, t = threadIdx.x;
    if (bid < 128) {
        __shared__ float tile[64][65];
        int m = bid >> 5, tl = bid & 31;
        const float* src; bf16_t* dst; int R, C, tr, tc; float scale = 1.0f;
        if (m < 3) {
            src = (m == 0) ? Wq : (m == 1) ? Wk : Wv;
            dst = (m == 0) ? WqT : (m == 1) ? WkT : WvT;
            R = 128; C = 1024; tr = tl >> 4; tc = tl & 15;
            if (m == 0) scale = QSCL;
        } else {
            src = Wo; dst = WoT; R = 1024; C = 128; tr = tl >> 1; tc = tl & 1;
        }
        int r0 = tr * 64, c0 = tc * 64;
        int rr = t >> 2, cc = (t & 3) * 16;
        const float4* s4 = (const float4*)(src + (size_t)(r0 + rr) * C + c0 + cc);
        #pragma unroll
        for (int i = 0; i < 4; ++i) {
            float4 f = s4[i];
            tile[rr][cc + 4 * i + 0] = f.x; tile[rr][cc + 4 * i + 1] = f.y;
            tile[rr][cc + 4 * i + 2] = f.z; tile[rr][cc + 4 * i + 3] = f.w;
        }
        __syncthreads();
        bf16x8 o0, o1;
        #pragma unroll
        for (int i = 0; i < 8; ++i) o0[i] = (bf16_t)(tile[cc + i][rr] * scale);
        #pragma unroll
        for (int i = 0; i < 8; ++i) o1[i] = (bf16_t)(tile[cc + 8 + i][rr] * scale);
        bf16_t* d = dst + (size_t)(c0 + rr) * R + r0 + cc;
        *(bf16x8*)d = o0;
        *(bf16x8*)(d + 8) = o1;
    } else {
        int bid2 = bid - 128;
        size_t base = (size_t)bid2 * 4096 + t * 16;
        int z = (int)(base >> 20);
        size_t off = base & 1048575;
        const float* s = (z == 0) ? q : (z == 1) ? k : v;
        const float4* s4 = (const float4*)(s + off);
        bf16_t* d = Abf + (size_t)z * 1048576 + off;
        float4 f0 = s4[0], f1 = s4[1], f2 = s4[2], f3 = s4[3];
        bf16x8 p0 = { (bf16_t)f0.x, (bf16_t)f0.y, (bf16_t)f0.z, (bf16_t)f0.w,
                      (bf16_t)f1.x, (bf16_t)f1.y, (bf16_t)f1.z, (bf16_t)f1.w };
        bf16x8 p1 = { (bf16_t)f2.x, (bf16_t)f2.y, (bf16_t)f2.z, (bf16_t)f2.w,
                      (bf16_t)f3.x, (bf16_t)f3.y, (bf16_t)f3.z, (bf16_t)f3.w };
        *(bf16x8*)d = p0;
        *(bf16x8*)(d + 8) = p1;
    }
}

// ---------------------------------------------------------------------------
// QKV projection: z=0 Q, z=1 K -> [B][H][S][D]; z=2 V -> [B][H][D][S].
// 128x128 tile, K=128 in 2 DMA double-buffered chunks. Epilogue transposes
// through LDS so ALL global stores are coalesced b128 row stores.
// ---------------------------------------------------------------------------
__global__ __launch_bounds__(256, 2)
void proj_kernel(const bf16_t* __restrict__ Abf,
                 const bf16_t* __restrict__ WqT, const bf16_t* __restrict__ WkT,
                 const bf16_t* __restrict__ WvT,
                 const float* __restrict__ bq, const float* __restrict__ bk,
                 const float* __restrict__ bv,
                 bf16_t* __restrict__ Qh, bf16_t* __restrict__ Kh, bf16_t* __restrict__ VhT)
{
    __shared__ __align__(16) bf16_t smem[2 * 2 * 128 * 64];  // 64 KB staging / transpose
    const int z = blockIdx.z;
    const bf16_t* A    = Abf + (size_t)z * 1048576;
    const bf16_t* BT   = (z == 0) ? WqT : (z == 1) ? WkT : WvT;
    const float*  bias = (z == 0) ? bq  : (z == 1) ? bk  : bv;
    const float   bscale = (z == 0) ? QSCL : 1.0f;
    const int t = threadIdx.x, w = t >> 6, lane = t & 63, q = lane >> 4, ln = lane & 15;
    const int m0 = blockIdx.x * 128;
    const int n0 = blockIdx.y * 128;
    const int wm = (w & 1) * 64, wn = (w >> 1) * 64;

    auto stage = [&](int buf, int kb) {
        bf16_t* as = smem + buf * 16384;
        bf16_t* bs = smem + buf * 16384 + 8192;
        #pragma unroll
        for (int j = 0; j < 4; ++j) {
            int row = w * 32 + j * 8 + (lane >> 3);
            int u = (lane & 7) ^ (row & 7);
            dma16(A + (size_t)(m0 + row) * 128 + kb * 64 + u * 8,
                  &as[(w * 32 + j * 8) * 64]);
            dma16(BT + (size_t)(n0 + row) * 128 + kb * 64 + u * 8,
                  &bs[(w * 32 + j * 8) * 64]);
        }
    };

    f32x4 acc[4][4] = {};
    stage(0, 0);
    __syncthreads();
    stage(1, 1);
    #pragma unroll
    for (int kb = 0; kb < 2; ++kb) {
        if (kb == 1) __syncthreads();
        const bf16_t* as = smem + kb * 16384;
        const bf16_t* bs = smem + kb * 16384 + 8192;
        #pragma unroll
        for (int kc = 0; kc < 2; ++kc) {
            bf16x8 af[4], bfr[4];
            #pragma unroll
            for (int mi = 0; mi < 4; ++mi)
                af[mi] = *(const bf16x8*)&as[(wm + mi * 16 + ln) * 64 + (((kc * 4 + q) ^ (ln & 7)) * 8)];
            #pragma unroll
            for (int ni = 0; ni < 4; ++ni)
                bfr[ni] = *(const bf16x8*)&bs[(wn + ni * 16 + ln) * 64 + (((kc * 4 + q) ^ (ln & 7)) * 8)];
            #pragma unroll
            for (int mi = 0; mi < 4; ++mi)
                #pragma unroll
                for (int ni = 0; ni < 4; ++ni)
                    acc[mi][ni] = MFMA_BF16(af[mi], bfr[ni], acc[mi][ni], 0, 0, 0);
        }
    }
    __syncthreads();   // done reading staging LDS; reuse as transpose buffer
    bf16_t* tb = smem; // stride 136 elements per row, 128 rows = 34.8 KB
    #pragma unroll
    for (int ni = 0; ni < 4; ++ni) {
        int col = wn + ni * 16 + ln;            // local n (d)
        float bvv = bias[n0 + col] * bscale;
        #pragma unroll
        for (int mi = 0; mi < 4; ++mi) {
            #pragma unroll
            for (int r = 0; r < 4; ++r) {
                int rowm = wm + mi * 16 + q * 4 + r;   // local m (s)
                bf16_t val = (bf16_t)(acc[mi][ni][r] + bvv);
                if (z != 2) tb[rowm * 136 + col] = val;   // [s][d]
                else        tb[col * 136 + rowm] = val;   // [d][s]
            }
        }
    }
    __syncthreads();
    {
        int row = t >> 1, half = t & 1;
        const bf16_t* src = tb + row * 136 + half * 64;
        const int b = m0 >> 11, s0 = m0 & 2047, h = n0 >> 7;
        bf16_t* dst;
        if (z != 2)  // Qh/Kh: row = s_local, 256B rows
            dst = ((z == 0) ? Qh : Kh) + ((size_t)((b * HH + h) * SS) + s0 + row) * 128 + half * 64;
        else         // VhT: row = d_local, cols s
            dst = VhT + ((size_t)((b * HH + h) * 128 + row)) * SS + s0 + half * 64;
        #pragma unroll
        for (int i = 0; i < 8; ++i)
            *(bf16x8*)(dst + i * 8) = *(const bf16x8*)(src + i * 8);
    }
}

// ---------------------------------------------------------------------------
// Attention v3: 32x32x16 MFMA. Block = (bh, 256 q-rows), 4 waves x 64 rows.
// KV tiles of 64 keys, DMA double-buffered + XOR-swizzled, 1 barrier/iter.
// Scores in log2 domain; l accumulated in-lane (no extra MFMA); P via
// wave-private swizzled LDS. ~250 VGPR, 1 block/CU by design.
// ---------------------------------------------------------------------------
__global__ __launch_bounds__(256, 1)
void attn_kernel(const bf16_t* __restrict__ Qh, const bf16_t* __restrict__ Kh,
                 const bf16_t* __restrict__ VhT, bf16_t* __restrict__ Aout)
{
    __shared__ __align__(16) bf16_t k_s[2][64 * 128];   // [key][dim] 16 units/row
    __shared__ __align__(16) bf16_t v_s[2][128 * 64];   // [dim][key] 8 units/row
    __shared__ __align__(16) bf16_t p_s[4][64 * 64];    // per-wave [qrow][key]
    __shared__ float l_lds[4][64];
    const int t = threadIdx.x;
    const int w = t >> 6, lane = t & 63;
    const int hh = lane >> 5, l31 = lane & 31;
    const int bh = blockIdx.y;
    const int q0 = blockIdx.x * 256;
    const int qw0 = q0 + w * 64;
    const size_t hb = (size_t)bh * SS * 128;

    // Q fragments (B-operand): lane holds qrow = ni*32+l31, dims c*16 + hh*8 + j
    bf16x8 qf[2][8];
    #pragma unroll
    for (int ni = 0; ni < 2; ++ni) {
        const bf16_t* qrow = Qh + hb + (size_t)(qw0 + ni * 32 + l31) * 128 + hh * 8;
        #pragma unroll
        for (int c = 0; c < 8; ++c)
            qf[ni][c] = *(const bf16x8*)(qrow + c * 16);
    }
    f32x16 o[2][4] = {};            // [qrow-tile][dout-tile]
    float lsum[2] = {0.f, 0.f};
    bf16_t* pw = p_s[w];

    auto stage = [&](int buf, int kv0) {
        #pragma unroll
        for (int j = 0; j < 4; ++j) {           // K: 4 rows (16 units) per call
            int row = w * 16 + j * 4 + (lane >> 4);
            int u = (lane & 15) ^ (row & 15);
            dma16(Kh + hb + (size_t)(kv0 + row) * 128 + u * 8,
                  &k_s[buf][(w * 16 + j * 4) * 128]);
        }
        #pragma unroll
        for (int j = 0; j < 4; ++j) {           // V: 8 rows (8 units) per call
            int row = w * 32 + j * 8 + (lane >> 3);
            int u = (lane & 7) ^ (row & 7);
            dma16(VhT + hb + (size_t)row * SS + kv0 + u * 8,
                  &v_s[buf][(w * 32 + j * 8) * 64]);
        }
    };

    stage(0, 0);
    for (int it = 0; it < SS / 64; ++it) {
        const int cur = it & 1;
        __syncthreads();                        // publish tile `it` (drains DMA)
        if (it + 1 < SS / 64) stage(cur ^ 1, (it + 1) * 64);
        const bf16_t* ks = k_s[cur];
        const bf16_t* vs = v_s[cur];

        // S^T = K * Q^T, 32x32 tiles: C[key][qrow]; then exp2 + P + l
        #pragma unroll
        for (int mi = 0; mi < 2; ++mi) {
            const int krow = mi * 32 + l31;
            const bf16_t* kb = ks + krow * 128;
            const int ksw = krow & 15;
            f32x16 s0 = {}, s1 = {};
            #pragma unroll
            for (int c = 0; c < 8; ++c) {
                bf16x8 kf = *(const bf16x8*)&kb[((2 * c + hh) ^ ksw) * 8];
                s0 = MFMA32(kf, qf[0][c], s0, 0, 0, 0);
                s1 = MFMA32(kf, qf[1][c], s1, 0, 0, 0);
            }
            const int psw = l31 & 7;
            #pragma unroll
            for (int ni = 0; ni < 2; ++ni) {
                const f32x16 sv = ni ? s1 : s0;
                bf16_t* prow = pw + (ni * 32 + l31) * 64 + hh * 4;
                float ls = 0.f;
                #pragma unroll
                for (int g = 0; g < 4; ++g) {
                    bf16x4 pk;
                    #pragma unroll
                    for (int r = 0; r < 4; ++r) {
                        float e = exp2_fast(sv[g * 4 + r]);
                        ls += e;
                        pk[r] = (bf16_t)e;
                    }
                    *(bf16x4*)&prow[((mi * 4 + g) ^ psw) * 8] = pk;
                }
                lsum[ni] += ls;
            }
        }
        // O += P * V  (A = P [qrow][key], B = V [key][dout])
        #pragma unroll
        for (int c = 0; c < 4; ++c) {
            bf16x8 vf[4];
            #pragma unroll
            for (int ni = 0; ni < 4; ++ni) {
                int drow = ni * 32 + l31;
                vf[ni] = *(const bf16x8*)&vs[drow * 64 + (((2 * c + hh) ^ (drow & 7)) * 8)];
            }
            #pragma unroll
            for (int mp = 0; mp < 2; ++mp) {
                int prow = mp * 32 + l31;
                bf16x8 pf = *(const bf16x8*)&pw[prow * 64 + (((2 * c + hh) ^ (prow & 7)) * 8)];
                #pragma unroll
                for (int ni = 0; ni < 4; ++ni)
                    o[mp][ni] = MFMA32(pf, vf[ni], o[mp][ni], 0, 0, 0);
            }
        }
    }
    // epilogue: combine l halves (lane holds half the keys), publish per-wave
    lsum[0] += __shfl_xor(lsum[0], 32);
    lsum[1] += __shfl_xor(lsum[1], 32);
    if (hh == 0) {
        l_lds[w][l31] = lsum[0];
        l_lds[w][32 + l31] = lsum[1];
    }
    const int b = bh >> 3, hd = bh & 7;
    #pragma unroll
    for (int mp = 0; mp < 2; ++mp) {
        #pragma unroll
        for (int g = 0; g < 4; ++g) {
            #pragma unroll
            for (int r = 0; r < 4; ++r) {
                int qrl = mp * 32 + g * 8 + hh * 4 + r;
                float inv = 1.0f / l_lds[w][qrl];
                int s = qw0 + qrl;
                bf16_t* dst = Aout + ((size_t)(b * SS + s)) * 1024 + hd * 128;
                #pragma unroll
                for (int ni = 0; ni < 4; ++ni)
                    dst[ni * 32 + l31] = (bf16_t)(o[mp][ni][g * 4 + r] * inv);
            }
        }
    }
}

// ---------------------------------------------------------------------------
// Output projection: [8192][1024] @ WoT^T + bo -> fp32 d_out. Full K=1024,
// 16 DMA double-buffered steps. Tile 32m x 128n, 256 blocks.
// ---------------------------------------------------------------------------
__global__ __launch_bounds__(256, 2)
void out_gemm(const bf16_t* __restrict__ A, const bf16_t* __restrict__ BT,
              const float* __restrict__ bias, float* __restrict__ out)
{
    __shared__ __align__(16) bf16_t a_s[2][32 * 64];
    __shared__ __align__(16) bf16_t b_s[2][128 * 64];
    const int t = threadIdx.x, w = t >> 6, lane = t & 63, q = lane >> 4, ln = lane & 15;
    const int m0 = blockIdx.x * 32;
    const int mh = (w & 1) * 16, nh = (w >> 1) * 64;
    f32x4 acc[4] = {};

    auto stage = [&](int buf, int kk) {
        {
            int row = w * 8 + (lane >> 3);
            int u = (lane & 7) ^ (row & 7);
            dma16(A + (size_t)(m0 + row) * 1024 + kk + u * 8, &a_s[buf][(w * 8) * 64]);
        }
        #pragma unroll
        for (int j = 0; j < 4; ++j) {
            int row = w * 32 + j * 8 + (lane >> 3);
            int u = (lane & 7) ^ (row & 7);
            dma16(BT + (size_t)row * 1024 + kk + u * 8, &b_s[buf][(w * 32 + j * 8) * 64]);
        }
    };

    stage(0, 0);
    for (int kb = 0; kb < 16; ++kb) {
        __syncthreads();
        if (kb < 15) stage((kb + 1) & 1, (kb + 1) * 64);
        const bf16_t* as = a_s[kb & 1];
        const bf16_t* bs = b_s[kb & 1];
        #pragma unroll
        for (int kc = 0; kc < 2; ++kc) {
            bf16x8 af = *(const bf16x8*)&as[(mh + ln) * 64 + (((kc * 4 + q) ^ (ln & 7)) * 8)];
            #pragma unroll
            for (int ni = 0; ni < 4; ++ni) {
                int brow = nh + ni * 16 + ln;
                bf16x8 bfr = *(const bf16x8*)&bs[brow * 64 + (((kc * 4 + q) ^ (ln & 7)) * 8)];
                acc[ni] = MFMA_BF16(af, bfr, acc[ni], 0, 0, 0);
            }
        }
    }
    #pragma unroll
    for (int ni = 0; ni < 4; ++ni) {
        int col = nh + ni * 16 + ln;
        float bv = bias[col];
        #pragma unroll
        for (int r = 0; r < 4; ++r)
            out[(size_t)(m0 + mh + q * 4 + r) * 128 + col] = acc[ni][r] + bv;
    }
}

// ---------------------------------------------------------------------------
extern "C" void kernel_launch(void* const* d_in, const int* in_sizes, int n_in,
                              void* d_out, int out_size, void* d_ws, size_t ws_size,
                              hipStream_t stream)
{
    const float* q  = (const float*)d_in[0];
    const float* k  = (const float*)d_in[1];
    const float* v  = (const float*)d_in[2];
    const float* Wq = (const float*)d_in[3];
    const float* bq = (const float*)d_in[4];
    const float* Wk = (const float*)d_in[5];
    const float* bk = (const float*)d_in[6];
    const float* Wv = (const float*)d_in[7];
    const float* bv = (const float*)d_in[8];
    const float* Wo = (const float*)d_in[9];
    const float* bo = (const float*)d_in[10];
    float* out = (float*)d_out;

    char* ws = (char*)d_ws;
    bf16_t* WqT  = (bf16_t*)(ws + 0 * (1 << 18));
    bf16_t* WkT  = (bf16_t*)(ws + 1 * (1 << 18));
    bf16_t* WvT  = (bf16_t*)(ws + 2 * (1 << 18));
    bf16_t* WoT  = (bf16_t*)(ws + 3 * (1 << 18));
    bf16_t* Abf  = (bf16_t*)(ws + (1 << 20));                   // [3][8192][128]
    bf16_t* Qh   = (bf16_t*)(ws + (1 << 23));                   // [B][H][S][128]
    bf16_t* Kh   = (bf16_t*)(ws + (1 << 23) + 1 * (1 << 24));   // [B][H][S][128]
    bf16_t* VhT  = (bf16_t*)(ws + (1 << 23) + 2 * (1 << 24));   // [B][H][128][S]
    bf16_t* Aout = (bf16_t*)(ws + (1 << 23) + 3 * (1 << 24));   // [B*S][1024]

    prep_kernel<<<896, 256, 0, stream>>>(q, k, v, Wq, Wk, Wv, Wo,
                                         WqT, WkT, WvT, WoT, Abf);
    proj_kernel<<<dim3(64, 8, 3), 256, 0, stream>>>(Abf, WqT, WkT, WvT,
                                                    bq, bk, bv, Qh, Kh, VhT);
    attn_kernel<<<dim3(SS / 256, BB * HH), 256, 0, stream>>>(Qh, Kh, VhT, Aout);
    out_gemm<<<256, 256, 0, stream>>>(Aout, WoT, bo, out);
}